// Round 8
// baseline (6130.854 us; speedup 1.0000x reference)
//
#include <hip/hip_runtime.h>
#include <stdint.h>
#include <math.h>

#define D_MODEL 1536
#define NH 12
#define HD 128
#define NL 12
#define SEQ 1024
#define D3 4608
#define D4 6144
#define SCALE 0.025515518153991442f  // 1/sqrt(1536)

typedef __attribute__((ext_vector_type(8))) short short8;
typedef __attribute__((ext_vector_type(4))) float floatx4;

// ---- trunc-based hi/lo split (round-4/7 semantics, bit-exact)
__device__ __forceinline__ uint32_t packhi(float a, float b) {
  return (__float_as_uint(a) >> 16) | (__float_as_uint(b) & 0xFFFF0000u);
}
__device__ __forceinline__ float truncf32(float a) {
  return __uint_as_float(__float_as_uint(a) & 0xFFFF0000u);
}
__device__ __forceinline__ void split8v(float4 v0, float4 v1, uint4 &hi, uint4 &lo) {
  hi.x = packhi(v0.x, v0.y); hi.y = packhi(v0.z, v0.w);
  hi.z = packhi(v1.x, v1.y); hi.w = packhi(v1.z, v1.w);
  lo.x = packhi(v0.x - truncf32(v0.x), v0.y - truncf32(v0.y));
  lo.y = packhi(v0.z - truncf32(v0.z), v0.w - truncf32(v0.w));
  lo.z = packhi(v1.x - truncf32(v1.x), v1.y - truncf32(v1.y));
  lo.w = packhi(v1.z - truncf32(v1.z), v1.w - truncf32(v1.w));
}

// bijective XCD-chunked block remap (m204)
__device__ __forceinline__ int xcd_chunk_id(int nwg) {
  int orig = blockIdx.x;
  int xcd = orig & 7, pos = orig >> 3;
  int q = nwg >> 3, r = nwg & 7;
  return (xcd < r ? xcd * (q + 1) : r * (q + 1) + (xcd - r) * q) + pos;
}

// ------------------------------------------------------------- embed
__global__ __launch_bounds__(256)
void embed_kernel(const int* __restrict__ idx, const float* __restrict__ tok,
                  const float* __restrict__ pos, float* __restrict__ x) {
  int i = blockIdx.x * 256 + threadIdx.x;
  int s = i / D_MODEL;
  int d = i - s * D_MODEL;
  x[i] = tok[(size_t)idx[s] * D_MODEL + d] + pos[d];  // pos row 0 quirk
}

// ------------------------------------------------------------- weight transpose+split
// W[K][N] f32 -> Th[N][K], Tl[N][K] bf16, TRUNC-split (verified r7)
__global__ __launch_bounds__(256)
void tsplit_kernel(const float* __restrict__ W, unsigned short* __restrict__ Th,
                   unsigned short* __restrict__ Tl, int K, int N) {
  __shared__ float T[64][65];
  const int tid = threadIdx.x;
  const int nt = N >> 6;
  const int tk = blockIdx.x / nt, tn = blockIdx.x - tk * nt;
  const float* Wl = W + (size_t)blockIdx.y * K * N;
  {
    int r = tid >> 2, q = tid & 3;
#pragma unroll
    for (int j = 0; j < 4; j++) {
      float4 v = *(const float4*)&Wl[(size_t)(tk * 64 + r) * N + tn * 64 + q * 16 + j * 4];
      T[r][q * 16 + j * 4 + 0] = v.x;
      T[r][q * 16 + j * 4 + 1] = v.y;
      T[r][q * 16 + j * 4 + 2] = v.z;
      T[r][q * 16 + j * 4 + 3] = v.w;
    }
  }
  __syncthreads();
  {
    int n = tid >> 2, kq = tid & 3;
    size_t ob = (size_t)blockIdx.y * K * N + (size_t)(tn * 64 + n) * K + tk * 64 + kq * 16;
#pragma unroll
    for (int half = 0; half < 2; half++) {
      short8 h8, l8;
#pragma unroll
      for (int j = 0; j < 8; j++) {
        float f = T[kq * 16 + half * 8 + j][n];
        h8[j] = (short)(__float_as_uint(f) >> 16);               // trunc hi
        l8[j] = (short)(__float_as_uint(f - truncf32(f)) >> 16); // trunc lo
      }
      *(short8*)&Th[ob + half * 8] = h8;
      *(short8*)&Tl[ob + half * 8] = l8;
    }
  }
}

// ------------------------------------------------------------- hi/lo MFMA GEMM
// C = A[M,K] @ Bt^T, Bt pre-split [N][K] hi/lo. 3-pass. 128x128 tile, BK=32.
// Always split-K: raw f32 partial to C + z*M*N (epilogue in combineN).
template<int SPLITK>
__global__ __launch_bounds__(256)
void mgemm_kernel(const float* __restrict__ A,
                  const unsigned short* __restrict__ Bhi,
                  const unsigned short* __restrict__ Blo, int ldb,
                  float* __restrict__ C, int M, int N, int K, int NC, int NR) {
  __shared__ short Ah[128][40], Al[128][40];
  __shared__ short Bh[128][40], Bl[128][40];
  const int tid = threadIdx.x;
  const int lane = tid & 63, wave = tid >> 6;

  const int lid = xcd_chunk_id(NC * NR * SPLITK);
  const int z   = lid / (NC * NR);
  const int rem = lid - z * (NC * NR);
  const int ct  = rem / NR;
  const int rt  = rem - ct * NR;
  const int bm = rt << 7, bn = ct << 7;

  const int wm = (wave >> 1) << 6, wn = (wave & 1) << 6;
  const int fr = lane & 15, fk = (lane >> 4) << 3;
  const int Kc = K / SPLITK;
  const int kbase = z * Kc;

  floatx4 acc[4][4];
#pragma unroll
  for (int i = 0; i < 4; i++)
#pragma unroll
    for (int j = 0; j < 4; j++) acc[i][j] = (floatx4){0.f, 0.f, 0.f, 0.f};

  const int ar = tid >> 1;
  const int ac = (tid & 1) << 4;
  const int brow = tid >> 1;
  const int bcol = (tid & 1) << 4;
  const float* Ag = A + (size_t)(bm + ar) * K + kbase + ac;
  const unsigned short* Bhg = Bhi + (size_t)(bn + brow) * ldb + kbase + bcol;
  const unsigned short* Blg = Blo + (size_t)(bn + brow) * ldb + kbase + bcol;

  for (int k0 = 0; k0 < Kc; k0 += 32) {
    __syncthreads();
    {  // A: row-major contiguous f32, trunc split in-kernel
      float4 v0 = *(const float4*)(Ag + k0);
      float4 v1 = *(const float4*)(Ag + k0 + 4);
      float4 v2 = *(const float4*)(Ag + k0 + 8);
      float4 v3 = *(const float4*)(Ag + k0 + 12);
      uint4 hi, lo;
      split8v(v0, v1, hi, lo);
      *(uint4*)&Ah[ar][ac] = hi;
      *(uint4*)&Al[ar][ac] = lo;
      split8v(v2, v3, hi, lo);
      *(uint4*)&Ah[ar][ac + 8] = hi;
      *(uint4*)&Al[ar][ac + 8] = lo;
    }
    {  // B: pre-split, contiguous 16B loads
#pragma unroll
      for (int e = 0; e < 2; e++) {
        *(short8*)&Bh[brow][bcol + 8 * e] = *(const short8*)(Bhg + k0 + 8 * e);
        *(short8*)&Bl[brow][bcol + 8 * e] = *(const short8*)(Blg + k0 + 8 * e);
      }
    }
    __syncthreads();
    short8 ah[4], al[4], bh[4], bl[4];
#pragma unroll
    for (int i = 0; i < 4; i++) {
      ah[i] = *(const short8*)&Ah[wm + (i << 4) + fr][fk];
      al[i] = *(const short8*)&Al[wm + (i << 4) + fr][fk];
      bh[i] = *(const short8*)&Bh[wn + (i << 4) + fr][fk];
      bl[i] = *(const short8*)&Bl[wn + (i << 4) + fr][fk];
    }
#pragma unroll
    for (int i = 0; i < 4; i++)
#pragma unroll
      for (int j = 0; j < 4; j++) {
        acc[i][j] = __builtin_amdgcn_mfma_f32_16x16x32_bf16(ah[i], bh[j], acc[i][j], 0, 0, 0);
        acc[i][j] = __builtin_amdgcn_mfma_f32_16x16x32_bf16(ah[i], bl[j], acc[i][j], 0, 0, 0);
        acc[i][j] = __builtin_amdgcn_mfma_f32_16x16x32_bf16(al[i], bh[j], acc[i][j], 0, 0, 0);
      }
  }

  const int cr = (lane >> 4) << 2, cc = lane & 15;
  float* Cp = C + (size_t)z * M * N;
#pragma unroll
  for (int j = 0; j < 4; j++) {
    const int col = bn + wn + (j << 4) + cc;
#pragma unroll
    for (int i = 0; i < 4; i++) {
      const int row0 = bm + wm + (i << 4) + cr;
#pragma unroll
      for (int r = 0; r < 4; r++)
        Cp[(size_t)(row0 + r) * N + col] = acc[i][j][r];
    }
  }
}

// ------------------------------------------------------------- combineN (split-K merge + epilogue)
template<int NP, bool HASB, bool RES, bool RELU>
__global__ __launch_bounds__(256)
void combineN_kernel(const float* __restrict__ parts, size_t pstride,
                     const float* __restrict__ bias, const float* __restrict__ res,
                     float* __restrict__ C, int N) {
  const int i = (blockIdx.x * 256 + threadIdx.x) << 2;
  float4 r = *(const float4*)&parts[i];
#pragma unroll
  for (int zz = 1; zz < NP; zz++) {
    float4 a = *(const float4*)&parts[(size_t)zz * pstride + i];
    r.x += a.x; r.y += a.y; r.z += a.z; r.w += a.w;
  }
  if constexpr (HASB) {
    const int col = i % N;
    float4 bv = *(const float4*)&bias[col];
    r.x += bv.x; r.y += bv.y; r.z += bv.z; r.w += bv.w;
  }
  if constexpr (RES) {
    float4 rv = *(const float4*)&res[i];
    r.x += rv.x; r.y += rv.y; r.z += rv.z; r.w += rv.w;
  }
  if constexpr (RELU) {
    r.x = fmaxf(r.x, 0.f); r.y = fmaxf(r.y, 0.f);
    r.z = fmaxf(r.z, 0.f); r.w = fmaxf(r.w, 0.f);
  }
  *(float4*)&C[i] = r;
}

// ------------------------------------------------------------- scores (4-pass MFMA)
__global__ __launch_bounds__(256)
void scores_kernel(const float* __restrict__ qkv, float* __restrict__ scores) {
  __shared__ short Qh[128][40], Ql[128][40], Kh[128][40], Kl[128][40];
  const int tid = threadIdx.x;
  const int lane = tid & 63, wave = tid >> 6;

  const int lid = xcd_chunk_id(NH * 64);        // h*64 + bjt*8 + bit
  const int h = lid >> 6;
  const int bj = ((lid >> 3) & 7) << 7;
  const int bi = (lid & 7) << 7;

  const int wm = (wave >> 1) << 6, wn = (wave & 1) << 6;
  const int fr = lane & 15, fk = (lane >> 4) << 3;
  const float* Q = qkv + h * HD;
  const float* Kp = qkv + D_MODEL + h * HD;

  floatx4 acc[4][4];
#pragma unroll
  for (int i = 0; i < 4; i++)
#pragma unroll
    for (int j = 0; j < 4; j++) acc[i][j] = (floatx4){0.f, 0.f, 0.f, 0.f};

  const int ar = tid >> 1;
  const int ac = (tid & 1) << 4;

  for (int k0 = 0; k0 < HD; k0 += 32) {
    __syncthreads();
    {
      const float* Qp = Q + (size_t)(bi + ar) * D3 + k0 + ac;
#pragma unroll
      for (int e = 0; e < 2; e++) {
        float4 v0 = *(const float4*)(Qp + 8 * e);
        float4 v1 = *(const float4*)(Qp + 8 * e + 4);
        uint4 hi, lo; split8v(v0, v1, hi, lo);
        *(uint4*)&Qh[ar][ac + 8 * e] = hi;
        *(uint4*)&Ql[ar][ac + 8 * e] = lo;
      }
      const float* Kpp = Kp + (size_t)(bj + ar) * D3 + k0 + ac;
#pragma unroll
      for (int e = 0; e < 2; e++) {
        float4 v0 = *(const float4*)(Kpp + 8 * e);
        float4 v1 = *(const float4*)(Kpp + 8 * e + 4);
        uint4 hi, lo; split8v(v0, v1, hi, lo);
        *(uint4*)&Kh[ar][ac + 8 * e] = hi;
        *(uint4*)&Kl[ar][ac + 8 * e] = lo;
      }
    }
    __syncthreads();
    short8 qh[4], ql[4], kh[4], kl[4];
#pragma unroll
    for (int i = 0; i < 4; i++) {
      qh[i] = *(const short8*)&Qh[wm + (i << 4) + fr][fk];
      ql[i] = *(const short8*)&Ql[wm + (i << 4) + fr][fk];
      kh[i] = *(const short8*)&Kh[wn + (i << 4) + fr][fk];
      kl[i] = *(const short8*)&Kl[wn + (i << 4) + fr][fk];
    }
#pragma unroll
    for (int i = 0; i < 4; i++)
#pragma unroll
      for (int j = 0; j < 4; j++) {
        acc[i][j] = __builtin_amdgcn_mfma_f32_16x16x32_bf16(qh[i], kh[j], acc[i][j], 0, 0, 0);
        acc[i][j] = __builtin_amdgcn_mfma_f32_16x16x32_bf16(qh[i], kl[j], acc[i][j], 0, 0, 0);
        acc[i][j] = __builtin_amdgcn_mfma_f32_16x16x32_bf16(ql[i], kh[j], acc[i][j], 0, 0, 0);
        acc[i][j] = __builtin_amdgcn_mfma_f32_16x16x32_bf16(ql[i], kl[j], acc[i][j], 0, 0, 0);
      }
  }

  const int cr = (lane >> 4) << 2, cc = lane & 15;
  float* S = scores + (size_t)h * SEQ * SEQ;
#pragma unroll
  for (int j = 0; j < 4; j++) {
    const int col = bj + wn + (j << 4) + cc;
#pragma unroll
    for (int i = 0; i < 4; i++) {
      const int row0 = bi + wm + (i << 4) + cr;
#pragma unroll
      for (int r = 0; r < 4; r++) {
        float v = acc[i][j][r] * SCALE;
        S[(size_t)(row0 + r) * SEQ + col] = (col <= row0 + r) ? v : -1e30f;
      }
    }
  }
}

// ------------------------------------------------------------- column stats
__global__ __launch_bounds__(256)
void colstatA_kernel(const float* __restrict__ scores, float* __restrict__ pstats) {
  const int b = blockIdx.x;
  const int h = b >> 5;
  const int cc = (b >> 3) & 3;
  const int qc = b & 7;
  const int c = (cc << 8) + threadIdx.x;
  const int q0 = qc << 7;
  const float* Sc = scores + (size_t)h * SEQ * SEQ + c;
  float m = -1e30f, z = 0.f;
  for (int q = q0; q < q0 + 128; q++) {
    if (q >= c) {
      float sv = Sc[(size_t)q * SEQ];
      float mn = fmaxf(m, sv);
      z = z * expf(m - mn) + expf(sv - mn);
      m = mn;
    }
  }
  pstats[(size_t)((h * 8 + qc) * 2 + 0) * 1024 + c] = m;
  pstats[(size_t)((h * 8 + qc) * 2 + 1) * 1024 + c] = z;
}

__global__ __launch_bounds__(256)
void colstatB_kernel(const float* __restrict__ pstats, float* __restrict__ stats) {
  const int i = blockIdx.x * 256 + threadIdx.x;
  const int h = i >> 10, c = i & 1023;
  float m = -1e30f;
#pragma unroll
  for (int qc = 0; qc < 8; qc++)
    m = fmaxf(m, pstats[(size_t)((h * 8 + qc) * 2 + 0) * 1024 + c]);
  float z = 0.f;
#pragma unroll
  for (int qc = 0; qc < 8; qc++) {
    float pm = pstats[(size_t)((h * 8 + qc) * 2 + 0) * 1024 + c];
    float pz = pstats[(size_t)((h * 8 + qc) * 2 + 1) * 1024 + c];
    z += pz * expf(pm - m);
  }
  stats[h * 2048 + c] = m;
  stats[h * 2048 + 1024 + c] = 1.f / z;
}

// ------------------------------------------------------------- attn @ V (3-pass, splitK=4)
__global__ __launch_bounds__(256)
void av_kernel(const float* __restrict__ qkv, const float* __restrict__ scores,
               const float* __restrict__ stats, float* __restrict__ part) {
  __shared__ short Ph[64][40], Pl[64][40], Vh[128][40], Vl[128][40];
  const int tid = threadIdx.x;
  const int lane = tid & 63, wave = tid >> 6;

  const int lid = xcd_chunk_id(NH * 4 * 16);    // (h*4+z)*16 + y
  const int hz = lid >> 4;
  const int y = lid & 15;
  const int h = hz >> 2, z = hz & 3;
  const int bm = y << 6;

  const int wm = (wave >> 1) << 5, wn = (wave & 1) << 6;
  const int fr = lane & 15, fk = (lane >> 4) << 3;
  const float* S = scores + (size_t)h * SEQ * SEQ;
  const float* Mh = stats + h * 2048;
  const float* Rh = Mh + 1024;
  const float* V = qkv + 2 * D_MODEL + h * HD;

  floatx4 acc[2][4];
#pragma unroll
  for (int i = 0; i < 2; i++)
#pragma unroll
    for (int j = 0; j < 4; j++) acc[i][j] = (floatx4){0.f, 0.f, 0.f, 0.f};

  const int ar = tid >> 2;
  const int ac = (tid & 3) << 3;
  const int bc = tid & 127;
  const int bkq = (tid >> 7) << 4;

  for (int k0 = z * 256; k0 < z * 256 + 256; k0 += 32) {
    __syncthreads();
    {  // P = exp(s - M[k]) * rZ[k], trunc split
      const float* Sp = S + (size_t)(bm + ar) * SEQ + k0 + ac;
      float4 v0 = *(const float4*)(Sp);
      float4 v1 = *(const float4*)(Sp + 4);
      float t[8] = {v0.x, v0.y, v0.z, v0.w, v1.x, v1.y, v1.z, v1.w};
      float4 p0, p1;
      {
        int kk = k0 + ac;
        p0.x = expf(t[0] - Mh[kk + 0]) * Rh[kk + 0];
        p0.y = expf(t[1] - Mh[kk + 1]) * Rh[kk + 1];
        p0.z = expf(t[2] - Mh[kk + 2]) * Rh[kk + 2];
        p0.w = expf(t[3] - Mh[kk + 3]) * Rh[kk + 3];
        p1.x = expf(t[4] - Mh[kk + 4]) * Rh[kk + 4];
        p1.y = expf(t[5] - Mh[kk + 5]) * Rh[kk + 5];
        p1.z = expf(t[6] - Mh[kk + 6]) * Rh[kk + 6];
        p1.w = expf(t[7] - Mh[kk + 7]) * Rh[kk + 7];
      }
      uint4 hi, lo; split8v(p0, p1, hi, lo);
      *(uint4*)&Ph[ar][ac] = hi;
      *(uint4*)&Pl[ar][ac] = lo;
    }
    {  // V: strided gather -> [d][k]
      const float* Vp = V + (size_t)(k0 + bkq) * D3 + bc;
#pragma unroll
      for (int e = 0; e < 2; e++) {
        float4 u0, u1;
        u0.x = Vp[(size_t)(8 * e + 0) * D3]; u0.y = Vp[(size_t)(8 * e + 1) * D3];
        u0.z = Vp[(size_t)(8 * e + 2) * D3]; u0.w = Vp[(size_t)(8 * e + 3) * D3];
        u1.x = Vp[(size_t)(8 * e + 4) * D3]; u1.y = Vp[(size_t)(8 * e + 5) * D3];
        u1.z = Vp[(size_t)(8 * e + 6) * D3]; u1.w = Vp[(size_t)(8 * e + 7) * D3];
        uint4 hi, lo; split8v(u0, u1, hi, lo);
        *(uint4*)&Vh[bc][bkq + 8 * e] = hi;
        *(uint4*)&Vl[bc][bkq + 8 * e] = lo;
      }
    }
    __syncthreads();
    short8 ph[2], pl[2], vh[4], vl[4];
#pragma unroll
    for (int i = 0; i < 2; i++) {
      ph[i] = *(const short8*)&Ph[wm + (i << 4) + fr][fk];
      pl[i] = *(const short8*)&Pl[wm + (i << 4) + fr][fk];
    }
#pragma unroll
    for (int j = 0; j < 4; j++) {
      vh[j] = *(const short8*)&Vh[wn + (j << 4) + fr][fk];
      vl[j] = *(const short8*)&Vl[wn + (j << 4) + fr][fk];
    }
#pragma unroll
    for (int i = 0; i < 2; i++)
#pragma unroll
      for (int j = 0; j < 4; j++) {
        acc[i][j] = __builtin_amdgcn_mfma_f32_16x16x32_bf16(ph[i], vh[j], acc[i][j], 0, 0, 0);
        acc[i][j] = __builtin_amdgcn_mfma_f32_16x16x32_bf16(ph[i], vl[j], acc[i][j], 0, 0, 0);
        acc[i][j] = __builtin_amdgcn_mfma_f32_16x16x32_bf16(pl[i], vh[j], acc[i][j], 0, 0, 0);
      }
  }

  const int cr = (lane >> 4) << 2, cc = lane & 15;
  float* Cp = part + (size_t)z * SEQ * D_MODEL;
#pragma unroll
  for (int j = 0; j < 4; j++) {
    const int col = h * HD + wn + (j << 4) + cc;
#pragma unroll
    for (int i = 0; i < 2; i++) {
      const int row0 = bm + wm + (i << 4) + cr;
#pragma unroll
      for (int r = 0; r < 4; r++)
        Cp[(size_t)(row0 + r) * D_MODEL + col] = acc[i][j][r];
    }
  }
}

// ------------------------------------------------------------- final LN
__global__ __launch_bounds__(256)
void ln_kernel(const float* __restrict__ x, const float* __restrict__ g,
               const float* __restrict__ bb, float* __restrict__ y) {
  __shared__ float red[8];
  const int row = blockIdx.x;
  const float* xr = x + (size_t)row * D_MODEL;
  float v[6];
  float s = 0.f, sq = 0.f;
#pragma unroll
  for (int i = 0; i < 6; i++) {
    v[i] = xr[256 * i + threadIdx.x];
    s += v[i];
    sq += v[i] * v[i];
  }
#pragma unroll
  for (int off = 32; off >= 1; off >>= 1) {
    s += __shfl_down(s, off, 64);
    sq += __shfl_down(sq, off, 64);
  }
  const int lane = threadIdx.x & 63, w = threadIdx.x >> 6;
  if (lane == 0) { red[w] = s; red[4 + w] = sq; }
  __syncthreads();
  if (threadIdx.x == 0) {
    red[0] = red[0] + red[1] + red[2] + red[3];
    red[4] = red[4] + red[5] + red[6] + red[7];
  }
  __syncthreads();
  const float mu = red[0] * (1.f / D_MODEL);
  const float var = red[4] * (1.f / D_MODEL) - mu * mu;
  const float rs = rsqrtf(var + 1e-5f);
#pragma unroll
  for (int i = 0; i < 6; i++) {
    int c = 256 * i + threadIdx.x;
    y[(size_t)row * D_MODEL + c] = (v[i] - mu) * rs * g[c] + bb[c];
  }
}

// ------------------------------------------------------------- launcher
extern "C" void kernel_launch(void* const* d_in, const int* in_sizes, int n_in,
                              void* d_out, int out_size, void* d_ws, size_t ws_size,
                              hipStream_t stream) {
  (void)in_sizes; (void)n_in; (void)out_size; (void)ws_size;
  typedef unsigned short u16;
  const int*   idx     = (const int*)d_in[0];
  const float* tok_emb = (const float*)d_in[2];
  const float* pos_emb = (const float*)d_in[3];
  const float* Wqkv    = (const float*)d_in[4];
  const float* bqkv    = (const float*)d_in[5];
  const float* Wo      = (const float*)d_in[6];
  const float* bo      = (const float*)d_in[7];
  const float* W1      = (const float*)d_in[8];
  const float* b1      = (const float*)d_in[9];
  const float* W2      = (const float*)d_in[10];
  const float* b2      = (const float*)d_in[11];
  const float* ln_g    = (const float*)d_in[12];
  const float* ln_b    = (const float*)d_in[13];
  const float* Wout    = (const float*)d_in[14];
  const float* bout    = (const float*)d_in[15];
  float* out = (float*)d_out;

  char* ws = (char*)d_ws;
  float* x      = (float*)(ws);                  //  6.29 MB
  float* qkv    = (float*)(ws + 6291456);        // 18.87 MB (also xn reuse)
  float* o      = (float*)(ws + 25165824);       //  6.29 MB
  float* stats  = (float*)(ws + 31457280);       //  0.10 MB
  float* pstats = (float*)(ws + 31555584);       //  0.79 MB
  float* h1     = (float*)(ws + 32342016);       // 25.17 MB
  float* part   = (float*)(ws + 57507840);       // 50.33 MB (split-K partials)
  float* scores = (float*)(ws + 107839488);      // 50.33 MB
  float* xn     = qkv;                           // reuse qkv region post-loop
  // transposed trunc-split weights (1.37 GB)
  u16* WQh = (u16*)(ws + 158171136);                    // [12][4608][1536]
  u16* WQl = WQh + (size_t)12 * 4608 * 1536;
  u16* WOh = WQl + (size_t)12 * 4608 * 1536;            // [12][1536][1536]
  u16* WOl = WOh + (size_t)12 * 1536 * 1536;
  u16* W1h = WOl + (size_t)12 * 1536 * 1536;            // [12][6144][1536]
  u16* W1l = W1h + (size_t)12 * 6144 * 1536;
  u16* W2h = W1l + (size_t)12 * 6144 * 1536;            // [12][1536][6144]
  u16* W2l = W2h + (size_t)12 * 1536 * 6144;
  u16* WUh = W2l + (size_t)12 * 1536 * 6144;            // [1536][1536]
  u16* WUl = WUh + (size_t)1536 * 1536;
  const size_t PN  = (size_t)SEQ * D_MODEL;   // 1536-col partial stride
  const size_t PNQ = (size_t)SEQ * D3;        // qkv partial stride
  const size_t PNH = (size_t)SEQ * D4;        // ffn1 partial stride

  // ---- pre-pass: transpose+split all weights (verified r7)
  tsplit_kernel<<<dim3(24 * 72, 12), 256, 0, stream>>>(Wqkv, WQh, WQl, 1536, 4608);
  tsplit_kernel<<<dim3(24 * 24, 12), 256, 0, stream>>>(Wo,   WOh, WOl, 1536, 1536);
  tsplit_kernel<<<dim3(24 * 96, 12), 256, 0, stream>>>(W1,   W1h, W1l, 1536, 6144);
  tsplit_kernel<<<dim3(96 * 24, 12), 256, 0, stream>>>(W2,   W2h, W2l, 6144, 1536);
  tsplit_kernel<<<dim3(24 * 24, 1),  256, 0, stream>>>(Wout, WUh, WUl, 1536, 1536);

  embed_kernel<<<6144, 256, 0, stream>>>(idx, tok_emb, pos_emb, x);

  for (int l = 0; l < NL; l++) {
    const float* bq  = bqkv + (size_t)l * D3;
    const float* bo_ = bo   + (size_t)l * D_MODEL;
    const float* b1_ = b1   + (size_t)l * D4;
    const float* b2_ = b2   + (size_t)l * D_MODEL;
    u16* wqh = WQh + (size_t)l * 4608 * 1536;
    u16* wql = WQl + (size_t)l * 4608 * 1536;
    u16* woh = WOh + (size_t)l * 1536 * 1536;
    u16* wol = WOl + (size_t)l * 1536 * 1536;
    u16* w1h = W1h + (size_t)l * 6144 * 1536;
    u16* w1l = W1l + (size_t)l * 6144 * 1536;
    u16* w2h = W2h + (size_t)l * 1536 * 6144;
    u16* w2l = W2l + (size_t)l * 1536 * 6144;

    // qkv = x @ Wqkv + bq   (splitK=2 -> 576 blocks)
    mgemm_kernel<2><<<576, 256, 0, stream>>>(
        x, wqh, wql, 1536, part, SEQ, D3, D_MODEL, 36, 8);
    combineN_kernel<2, true, false, false><<<4608, 256, 0, stream>>>(
        part, PNQ, bq, nullptr, qkv, D3);
    // attention
    scores_kernel<<<768, 256, 0, stream>>>(qkv, scores);
    colstatA_kernel<<<384, 256, 0, stream>>>(scores, pstats);
    colstatB_kernel<<<48, 256, 0, stream>>>(pstats, stats);
    av_kernel<<<768, 256, 0, stream>>>(qkv, scores, stats, part);
    combineN_kernel<4, false, false, false><<<1536, 256, 0, stream>>>(
        part, PN, nullptr, nullptr, o, D_MODEL);
    // x += o @ Wo + bo   (splitK=6 -> 576 blocks)
    mgemm_kernel<6><<<576, 256, 0, stream>>>(
        o, woh, wol, 1536, part, SEQ, D_MODEL, D_MODEL, 12, 8);
    combineN_kernel<6, true, true, false><<<1536, 256, 0, stream>>>(
        part, PN, bo_, x, x, D_MODEL);
    // h1 = relu(x @ W1 + b1)   (splitK=2 -> 768 blocks)
    mgemm_kernel<2><<<768, 256, 0, stream>>>(
        x, w1h, w1l, 1536, part, SEQ, D4, D_MODEL, 48, 8);
    combineN_kernel<2, true, false, true><<<6144, 256, 0, stream>>>(
        part, PNH, b1_, nullptr, h1, D4);
    // x += h1 @ W2 + b2   (splitK=6 -> 576 blocks)
    mgemm_kernel<6><<<576, 256, 0, stream>>>(
        h1, w2h, w2l, 6144, part, SEQ, D_MODEL, D4, 12, 8);
    combineN_kernel<6, true, true, false><<<1536, 256, 0, stream>>>(
        part, PN, b2_, x, x, D_MODEL);
  }

  ln_kernel<<<SEQ, 256, 0, stream>>>(x, ln_g, ln_b, xn);
  mgemm_kernel<6><<<576, 256, 0, stream>>>(
      xn, WUh, WUl, 1536, part, SEQ, D_MODEL, D_MODEL, 12, 8);
  combineN_kernel<6, true, false, false><<<1536, 256, 0, stream>>>(
      part, PN, bout, nullptr, out, D_MODEL);
}

// Round 9
// 5708.839 us; speedup vs baseline: 1.0739x; 1.0739x over previous
//
#include <hip/hip_runtime.h>
#include <stdint.h>
#include <math.h>

#define D_MODEL 1536
#define NH 12
#define HD 128
#define NL 12
#define SEQ 1024
#define D3 4608
#define D4 6144
#define SCALE 0.025515518153991442f  // 1/sqrt(1536)

typedef __attribute__((ext_vector_type(8))) short short8;
typedef __attribute__((ext_vector_type(4))) float floatx4;

// ---- trunc-based hi/lo split (round-4 semantics, bit-exact)
__device__ __forceinline__ uint32_t packhi(float a, float b) {
  return (__float_as_uint(a) >> 16) | (__float_as_uint(b) & 0xFFFF0000u);
}
__device__ __forceinline__ float truncf32(float a) {
  return __uint_as_float(__float_as_uint(a) & 0xFFFF0000u);
}
__device__ __forceinline__ void split8v(float4 v0, float4 v1, uint4 &hi, uint4 &lo) {
  hi.x = packhi(v0.x, v0.y); hi.y = packhi(v0.z, v0.w);
  hi.z = packhi(v1.x, v1.y); hi.w = packhi(v1.z, v1.w);
  lo.x = packhi(v0.x - truncf32(v0.x), v0.y - truncf32(v0.y));
  lo.y = packhi(v0.z - truncf32(v0.z), v0.w - truncf32(v0.w));
  lo.z = packhi(v1.x - truncf32(v1.x), v1.y - truncf32(v1.y));
  lo.w = packhi(v1.z - truncf32(v1.z), v1.w - truncf32(v1.w));
}

// bijective XCD-chunked block remap (m204)
__device__ __forceinline__ int xcd_chunk_id(int nwg) {
  int orig = blockIdx.x;
  int xcd = orig & 7, pos = orig >> 3;
  int q = nwg >> 3, r = nwg & 7;
  return (xcd < r ? xcd * (q + 1) : r * (q + 1) + (xcd - r) * q) + pos;
}

// ------------------------------------------------------------- embed
__global__ __launch_bounds__(256)
void embed_kernel(const int* __restrict__ idx, const float* __restrict__ tok,
                  const float* __restrict__ pos, float* __restrict__ x) {
  int i = blockIdx.x * 256 + threadIdx.x;
  int s = i / D_MODEL;
  int d = i - s * D_MODEL;
  x[i] = tok[(size_t)idx[s] * D_MODEL + d] + pos[d];  // pos row 0 quirk
}

// ------------------------------------------------------------- hi/lo MFMA GEMM (PIPELINED)
// C = A[M,K] @ B[K,N]; 3-pass (AhBh+AhBl+AlBh). BM x 128 tile, BK=32, 4 waves.
// Reg-staged double-buffered LDS: per K-step {issue t+1 global loads -> regs;
// ds_read+MFMA on buf[cur]; split+ds_write regs -> buf[cur^1]; one barrier}.
// LDS rows padded to 36 shorts (72B): banks (18r+4q)%32 distinct for r=0..15.
template<int BM, bool RELU, bool RES, int SPLITK>
__global__ __launch_bounds__(256)
void mgemm_kernel(const float* __restrict__ A, const float* __restrict__ B,
                  const float* __restrict__ bias, const float* __restrict__ res,
                  float* __restrict__ C, int M, int N, int K, int NC, int NR) {
  constexpr int MI = BM / 32;          // a-frags per wave
  constexpr int AE = BM / 8;           // A floats per thread per k-step
  constexpr int TPR = 32 / AE;         // threads per A row
  __shared__ short Ah[2][BM][36], Al[2][BM][36];
  __shared__ short Bh[2][128][36], Bl[2][128][36];
  const int tid = threadIdx.x;
  const int lane = tid & 63, wave = tid >> 6;

  const int lid = xcd_chunk_id(NC * NR * SPLITK);
  const int z   = lid / (NC * NR);
  const int rem = lid - z * (NC * NR);
  const int ct  = rem / NR;
  const int rt  = rem - ct * NR;
  const int bm = rt * BM, bn = ct << 7;

  const int wm = (wave >> 1) * (BM / 2), wn = (wave & 1) << 6;
  const int fr = lane & 15, fk = (lane >> 4) << 3;
  const int Kc = K / SPLITK;
  const int kbase = (SPLITK > 1) ? z * Kc : 0;

  floatx4 acc[MI][4];
#pragma unroll
  for (int i = 0; i < MI; i++)
#pragma unroll
    for (int j = 0; j < 4; j++) acc[i][j] = (floatx4){0.f, 0.f, 0.f, 0.f};

  const int ar = tid / TPR;
  const int ac = (tid % TPR) * AE;
  const int bc = tid & 127;
  const int bkq = (tid >> 7) << 4;
  const float* Ag = A + (size_t)(bm + ar) * K + kbase + ac;
  const float* Bg = B + (size_t)(kbase + bkq) * N + bn + bc;

  float a_reg[AE];
  float b_reg[16];

  auto LOADG = [&](int k0) {
#pragma unroll
    for (int e = 0; e < AE / 4; e++) {
      float4 v = *(const float4*)(Ag + k0 + 4 * e);
      a_reg[4 * e + 0] = v.x; a_reg[4 * e + 1] = v.y;
      a_reg[4 * e + 2] = v.z; a_reg[4 * e + 3] = v.w;
    }
    const float* Bp = Bg + (size_t)k0 * N;
#pragma unroll
    for (int j = 0; j < 16; j++) b_reg[j] = Bp[(size_t)j * N];
  };
  auto STORE = [&](int buf) {
#pragma unroll
    for (int e = 0; e < AE / 8; e++) {
      float4 v0 = {a_reg[8 * e + 0], a_reg[8 * e + 1], a_reg[8 * e + 2], a_reg[8 * e + 3]};
      float4 v1 = {a_reg[8 * e + 4], a_reg[8 * e + 5], a_reg[8 * e + 6], a_reg[8 * e + 7]};
      uint4 hi, lo; split8v(v0, v1, hi, lo);
      *(uint4*)&Ah[buf][ar][ac + 8 * e] = hi;
      *(uint4*)&Al[buf][ar][ac + 8 * e] = lo;
    }
#pragma unroll
    for (int e = 0; e < 2; e++) {
      float4 u0 = {b_reg[8 * e + 0], b_reg[8 * e + 1], b_reg[8 * e + 2], b_reg[8 * e + 3]};
      float4 u1 = {b_reg[8 * e + 4], b_reg[8 * e + 5], b_reg[8 * e + 6], b_reg[8 * e + 7]};
      uint4 hi, lo; split8v(u0, u1, hi, lo);
      *(uint4*)&Bh[buf][bc][bkq + 8 * e] = hi;
      *(uint4*)&Bl[buf][bc][bkq + 8 * e] = lo;
    }
  };

  LOADG(0);
  STORE(0);
  __syncthreads();

  for (int k0 = 0; k0 < Kc; k0 += 32) {
    const int cur = (k0 >> 5) & 1;
    const bool more = (k0 + 32 < Kc);
    if (more) LOADG(k0 + 32);          // global latency hides under MFMA below

    short8 ah[MI], al[MI], bh[4], bl[4];
#pragma unroll
    for (int i = 0; i < MI; i++) {
      ah[i] = *(const short8*)&Ah[cur][wm + (i << 4) + fr][fk];
      al[i] = *(const short8*)&Al[cur][wm + (i << 4) + fr][fk];
    }
#pragma unroll
    for (int j = 0; j < 4; j++) {
      bh[j] = *(const short8*)&Bh[cur][wn + (j << 4) + fr][fk];
      bl[j] = *(const short8*)&Bl[cur][wn + (j << 4) + fr][fk];
    }
#pragma unroll
    for (int i = 0; i < MI; i++)
#pragma unroll
      for (int j = 0; j < 4; j++) {
        acc[i][j] = __builtin_amdgcn_mfma_f32_16x16x32_bf16(ah[i], bh[j], acc[i][j], 0, 0, 0);
        acc[i][j] = __builtin_amdgcn_mfma_f32_16x16x32_bf16(ah[i], bl[j], acc[i][j], 0, 0, 0);
        acc[i][j] = __builtin_amdgcn_mfma_f32_16x16x32_bf16(al[i], bh[j], acc[i][j], 0, 0, 0);
      }

    if (more) STORE(cur ^ 1);          // writes other buffer; safe pre-barrier
    __syncthreads();
  }

  const int cr = (lane >> 4) << 2, cc = lane & 15;
  if constexpr (SPLITK > 1) {
    float* Cp = C + (size_t)z * M * N;
#pragma unroll
    for (int j = 0; j < 4; j++) {
      const int col = bn + wn + (j << 4) + cc;
#pragma unroll
      for (int i = 0; i < MI; i++) {
        const int row0 = bm + wm + (i << 4) + cr;
#pragma unroll
        for (int r = 0; r < 4; r++)
          Cp[(size_t)(row0 + r) * N + col] = acc[i][j][r];
      }
    }
  } else {
#pragma unroll
    for (int j = 0; j < 4; j++) {
      const int col = bn + wn + (j << 4) + cc;
      const float bv = bias[col];
#pragma unroll
      for (int i = 0; i < MI; i++) {
        const int row0 = bm + wm + (i << 4) + cr;
#pragma unroll
        for (int r = 0; r < 4; r++) {
          float v = acc[i][j][r] + bv;
          if constexpr (RES) v += res[(size_t)(row0 + r) * N + col];
          if constexpr (RELU) v = fmaxf(v, 0.f);
          C[(size_t)(row0 + r) * N + col] = v;
        }
      }
    }
  }
}

// ------------------------------------------------------------- combine (split-K)
template<bool HASB, bool RES, bool RELU>
__global__ __launch_bounds__(256)
void combine_kernel(const float* __restrict__ p0, const float* __restrict__ p1,
                    const float* __restrict__ bias, const float* __restrict__ res,
                    float* __restrict__ C, int N) {
  const int i = (blockIdx.x * 256 + threadIdx.x) << 2;
  float4 a = *(const float4*)&p0[i];
  float4 b = *(const float4*)&p1[i];
  float4 r = {a.x + b.x, a.y + b.y, a.z + b.z, a.w + b.w};
  if constexpr (HASB) {
    const int col = i % N;
    float4 bv = *(const float4*)&bias[col];
    r.x += bv.x; r.y += bv.y; r.z += bv.z; r.w += bv.w;
  }
  if constexpr (RES) {
    float4 rv = *(const float4*)&res[i];
    r.x += rv.x; r.y += rv.y; r.z += rv.z; r.w += rv.w;
  }
  if constexpr (RELU) {
    r.x = fmaxf(r.x, 0.f); r.y = fmaxf(r.y, 0.f);
    r.z = fmaxf(r.z, 0.f); r.w = fmaxf(r.w, 0.f);
  }
  *(float4*)&C[i] = r;
}

// ------------------------------------------------------------- scores (4-pass MFMA)
__global__ __launch_bounds__(256)
void scores_kernel(const float* __restrict__ qkv, float* __restrict__ scores) {
  __shared__ short Qh[128][40], Ql[128][40], Kh[128][40], Kl[128][40];
  const int tid = threadIdx.x;
  const int lane = tid & 63, wave = tid >> 6;

  const int lid = xcd_chunk_id(NH * 64);        // h*64 + bjt*8 + bit
  const int h = lid >> 6;
  const int bj = ((lid >> 3) & 7) << 7;
  const int bi = (lid & 7) << 7;

  const int wm = (wave >> 1) << 6, wn = (wave & 1) << 6;
  const int fr = lane & 15, fk = (lane >> 4) << 3;
  const float* Q = qkv + h * HD;
  const float* Kp = qkv + D_MODEL + h * HD;

  floatx4 acc[4][4];
#pragma unroll
  for (int i = 0; i < 4; i++)
#pragma unroll
    for (int j = 0; j < 4; j++) acc[i][j] = (floatx4){0.f, 0.f, 0.f, 0.f};

  const int ar = tid >> 1;
  const int ac = (tid & 1) << 4;

  for (int k0 = 0; k0 < HD; k0 += 32) {
    __syncthreads();
    {
      const float* Qp = Q + (size_t)(bi + ar) * D3 + k0 + ac;
#pragma unroll
      for (int e = 0; e < 2; e++) {
        float4 v0 = *(const float4*)(Qp + 8 * e);
        float4 v1 = *(const float4*)(Qp + 8 * e + 4);
        uint4 hi, lo; split8v(v0, v1, hi, lo);
        *(uint4*)&Qh[ar][ac + 8 * e] = hi;
        *(uint4*)&Ql[ar][ac + 8 * e] = lo;
      }
      const float* Kpp = Kp + (size_t)(bj + ar) * D3 + k0 + ac;
#pragma unroll
      for (int e = 0; e < 2; e++) {
        float4 v0 = *(const float4*)(Kpp + 8 * e);
        float4 v1 = *(const float4*)(Kpp + 8 * e + 4);
        uint4 hi, lo; split8v(v0, v1, hi, lo);
        *(uint4*)&Kh[ar][ac + 8 * e] = hi;
        *(uint4*)&Kl[ar][ac + 8 * e] = lo;
      }
    }
    __syncthreads();
    short8 qh[4], ql[4], kh[4], kl[4];
#pragma unroll
    for (int i = 0; i < 4; i++) {
      qh[i] = *(const short8*)&Qh[wm + (i << 4) + fr][fk];
      ql[i] = *(const short8*)&Ql[wm + (i << 4) + fr][fk];
      kh[i] = *(const short8*)&Kh[wn + (i << 4) + fr][fk];
      kl[i] = *(const short8*)&Kl[wn + (i << 4) + fr][fk];
    }
#pragma unroll
    for (int i = 0; i < 4; i++)
#pragma unroll
      for (int j = 0; j < 4; j++) {
        acc[i][j] = __builtin_amdgcn_mfma_f32_16x16x32_bf16(qh[i], kh[j], acc[i][j], 0, 0, 0);
        acc[i][j] = __builtin_amdgcn_mfma_f32_16x16x32_bf16(qh[i], kl[j], acc[i][j], 0, 0, 0);
        acc[i][j] = __builtin_amdgcn_mfma_f32_16x16x32_bf16(ql[i], kh[j], acc[i][j], 0, 0, 0);
        acc[i][j] = __builtin_amdgcn_mfma_f32_16x16x32_bf16(ql[i], kl[j], acc[i][j], 0, 0, 0);
      }
  }

  const int cr = (lane >> 4) << 2, cc = lane & 15;
  float* S = scores + (size_t)h * SEQ * SEQ;
#pragma unroll
  for (int j = 0; j < 4; j++) {
    const int col = bj + wn + (j << 4) + cc;
#pragma unroll
    for (int i = 0; i < 4; i++) {
      const int row0 = bi + wm + (i << 4) + cr;
#pragma unroll
      for (int r = 0; r < 4; r++) {
        float v = acc[i][j][r] * SCALE;
        S[(size_t)(row0 + r) * SEQ + col] = (col <= row0 + r) ? v : -1e30f;
      }
    }
  }
}

// ------------------------------------------------------------- column stats
__global__ __launch_bounds__(256)
void colstatA_kernel(const float* __restrict__ scores, float* __restrict__ pstats) {
  const int b = blockIdx.x;
  const int h = b >> 5;
  const int cc = (b >> 3) & 3;
  const int qc = b & 7;
  const int c = (cc << 8) + threadIdx.x;
  const int q0 = qc << 7;
  const float* Sc = scores + (size_t)h * SEQ * SEQ + c;
  float m = -1e30f, z = 0.f;
  for (int q = q0; q < q0 + 128; q++) {
    if (q >= c) {
      float sv = Sc[(size_t)q * SEQ];
      float mn = fmaxf(m, sv);
      z = z * expf(m - mn) + expf(sv - mn);
      m = mn;
    }
  }
  pstats[(size_t)((h * 8 + qc) * 2 + 0) * 1024 + c] = m;
  pstats[(size_t)((h * 8 + qc) * 2 + 1) * 1024 + c] = z;
}

__global__ __launch_bounds__(256)
void colstatB_kernel(const float* __restrict__ pstats, float* __restrict__ stats) {
  const int i = blockIdx.x * 256 + threadIdx.x;
  const int h = i >> 10, c = i & 1023;
  float m = -1e30f;
#pragma unroll
  for (int qc = 0; qc < 8; qc++)
    m = fmaxf(m, pstats[(size_t)((h * 8 + qc) * 2 + 0) * 1024 + c]);
  float z = 0.f;
#pragma unroll
  for (int qc = 0; qc < 8; qc++) {
    float pm = pstats[(size_t)((h * 8 + qc) * 2 + 0) * 1024 + c];
    float pz = pstats[(size_t)((h * 8 + qc) * 2 + 1) * 1024 + c];
    z += pz * expf(pm - m);
  }
  stats[h * 2048 + c] = m;
  stats[h * 2048 + 1024 + c] = 1.f / z;
}

// ------------------------------------------------------------- attn @ V (3-pass, splitK=2)
__global__ __launch_bounds__(256)
void av_kernel(const float* __restrict__ qkv, const float* __restrict__ scores,
               const float* __restrict__ stats, float* __restrict__ part) {
  __shared__ short Ph[64][40], Pl[64][40], Vh[128][40], Vl[128][40];
  const int tid = threadIdx.x;
  const int lane = tid & 63, wave = tid >> 6;

  const int lid = xcd_chunk_id(NH * 2 * 16);    // (h*2+z)*16 + y
  const int hz = lid >> 4;
  const int y = lid & 15;
  const int h = hz >> 1, z = hz & 1;
  const int bm = y << 6;

  const int wm = (wave >> 1) << 5, wn = (wave & 1) << 6;
  const int fr = lane & 15, fk = (lane >> 4) << 3;
  const float* S = scores + (size_t)h * SEQ * SEQ;
  const float* Mh = stats + h * 2048;
  const float* Rh = Mh + 1024;
  const float* V = qkv + 2 * D_MODEL + h * HD;

  floatx4 acc[2][4];
#pragma unroll
  for (int i = 0; i < 2; i++)
#pragma unroll
    for (int j = 0; j < 4; j++) acc[i][j] = (floatx4){0.f, 0.f, 0.f, 0.f};

  const int ar = tid >> 2;
  const int ac = (tid & 3) << 3;
  const int bc = tid & 127;
  const int bkq = (tid >> 7) << 4;

  for (int k0 = z * 512; k0 < z * 512 + 512; k0 += 32) {
    __syncthreads();
    {  // P = exp(s - M[k]) * rZ[k], trunc split
      const float* Sp = S + (size_t)(bm + ar) * SEQ + k0 + ac;
      float4 v0 = *(const float4*)(Sp);
      float4 v1 = *(const float4*)(Sp + 4);
      float t[8] = {v0.x, v0.y, v0.z, v0.w, v1.x, v1.y, v1.z, v1.w};
      float4 p0, p1;
      {
        int kk = k0 + ac;
        p0.x = expf(t[0] - Mh[kk + 0]) * Rh[kk + 0];
        p0.y = expf(t[1] - Mh[kk + 1]) * Rh[kk + 1];
        p0.z = expf(t[2] - Mh[kk + 2]) * Rh[kk + 2];
        p0.w = expf(t[3] - Mh[kk + 3]) * Rh[kk + 3];
        p1.x = expf(t[4] - Mh[kk + 4]) * Rh[kk + 4];
        p1.y = expf(t[5] - Mh[kk + 5]) * Rh[kk + 5];
        p1.z = expf(t[6] - Mh[kk + 6]) * Rh[kk + 6];
        p1.w = expf(t[7] - Mh[kk + 7]) * Rh[kk + 7];
      }
      uint4 hi, lo; split8v(p0, p1, hi, lo);
      *(uint4*)&Ph[ar][ac] = hi;
      *(uint4*)&Pl[ar][ac] = lo;
    }
    {  // V: strided gather -> [d][k]
      const float* Vp = V + (size_t)(k0 + bkq) * D3 + bc;
#pragma unroll
      for (int e = 0; e < 2; e++) {
        float4 u0, u1;
        u0.x = Vp[(size_t)(8 * e + 0) * D3]; u0.y = Vp[(size_t)(8 * e + 1) * D3];
        u0.z = Vp[(size_t)(8 * e + 2) * D3]; u0.w = Vp[(size_t)(8 * e + 3) * D3];
        u1.x = Vp[(size_t)(8 * e + 4) * D3]; u1.y = Vp[(size_t)(8 * e + 5) * D3];
        u1.z = Vp[(size_t)(8 * e + 6) * D3]; u1.w = Vp[(size_t)(8 * e + 7) * D3];
        uint4 hi, lo; split8v(u0, u1, hi, lo);
        *(uint4*)&Vh[bc][bkq + 8 * e] = hi;
        *(uint4*)&Vl[bc][bkq + 8 * e] = lo;
      }
    }
    __syncthreads();
    short8 ph[2], pl[2], vh[4], vl[4];
#pragma unroll
    for (int i = 0; i < 2; i++) {
      ph[i] = *(const short8*)&Ph[wm + (i << 4) + fr][fk];
      pl[i] = *(const short8*)&Pl[wm + (i << 4) + fr][fk];
    }
#pragma unroll
    for (int j = 0; j < 4; j++) {
      vh[j] = *(const short8*)&Vh[wn + (j << 4) + fr][fk];
      vl[j] = *(const short8*)&Vl[wn + (j << 4) + fr][fk];
    }
#pragma unroll
    for (int i = 0; i < 2; i++)
#pragma unroll
      for (int j = 0; j < 4; j++) {
        acc[i][j] = __builtin_amdgcn_mfma_f32_16x16x32_bf16(ph[i], vh[j], acc[i][j], 0, 0, 0);
        acc[i][j] = __builtin_amdgcn_mfma_f32_16x16x32_bf16(ph[i], vl[j], acc[i][j], 0, 0, 0);
        acc[i][j] = __builtin_amdgcn_mfma_f32_16x16x32_bf16(pl[i], vh[j], acc[i][j], 0, 0, 0);
      }
  }

  const int cr = (lane >> 4) << 2, cc = lane & 15;
  float* Cp = part + (size_t)z * SEQ * D_MODEL;
#pragma unroll
  for (int j = 0; j < 4; j++) {
    const int col = h * HD + wn + (j << 4) + cc;
#pragma unroll
    for (int i = 0; i < 2; i++) {
      const int row0 = bm + wm + (i << 4) + cr;
#pragma unroll
      for (int r = 0; r < 4; r++)
        Cp[(size_t)(row0 + r) * D_MODEL + col] = acc[i][j][r];
    }
  }
}

// ------------------------------------------------------------- final LN
__global__ __launch_bounds__(256)
void ln_kernel(const float* __restrict__ x, const float* __restrict__ g,
               const float* __restrict__ bb, float* __restrict__ y) {
  __shared__ float red[8];
  const int row = blockIdx.x;
  const float* xr = x + (size_t)row * D_MODEL;
  float v[6];
  float s = 0.f, sq = 0.f;
#pragma unroll
  for (int i = 0; i < 6; i++) {
    v[i] = xr[256 * i + threadIdx.x];
    s += v[i];
    sq += v[i] * v[i];
  }
#pragma unroll
  for (int off = 32; off >= 1; off >>= 1) {
    s += __shfl_down(s, off, 64);
    sq += __shfl_down(sq, off, 64);
  }
  const int lane = threadIdx.x & 63, w = threadIdx.x >> 6;
  if (lane == 0) { red[w] = s; red[4 + w] = sq; }
  __syncthreads();
  if (threadIdx.x == 0) {
    red[0] = red[0] + red[1] + red[2] + red[3];
    red[4] = red[4] + red[5] + red[6] + red[7];
  }
  __syncthreads();
  const float mu = red[0] * (1.f / D_MODEL);
  const float var = red[4] * (1.f / D_MODEL) - mu * mu;
  const float rs = rsqrtf(var + 1e-5f);
#pragma unroll
  for (int i = 0; i < 6; i++) {
    int c = 256 * i + threadIdx.x;
    y[(size_t)row * D_MODEL + c] = (v[i] - mu) * rs * g[c] + bb[c];
  }
}

// ------------------------------------------------------------- launcher
extern "C" void kernel_launch(void* const* d_in, const int* in_sizes, int n_in,
                              void* d_out, int out_size, void* d_ws, size_t ws_size,
                              hipStream_t stream) {
  (void)in_sizes; (void)n_in; (void)out_size; (void)ws_size;
  const int*   idx     = (const int*)d_in[0];
  const float* tok_emb = (const float*)d_in[2];
  const float* pos_emb = (const float*)d_in[3];
  const float* Wqkv    = (const float*)d_in[4];
  const float* bqkv    = (const float*)d_in[5];
  const float* Wo      = (const float*)d_in[6];
  const float* bo      = (const float*)d_in[7];
  const float* W1      = (const float*)d_in[8];
  const float* b1      = (const float*)d_in[9];
  const float* W2      = (const float*)d_in[10];
  const float* b2      = (const float*)d_in[11];
  const float* ln_g    = (const float*)d_in[12];
  const float* ln_b    = (const float*)d_in[13];
  const float* Wout    = (const float*)d_in[14];
  const float* bout    = (const float*)d_in[15];
  float* out = (float*)d_out;

  char* ws = (char*)d_ws;
  float* x      = (float*)(ws);                 //  6.29 MB
  float* qkv    = (float*)(ws + 6291456);       // 18.87 MB
  float* o      = (float*)(ws + 25165824);      //  6.29 MB
  float* stats  = (float*)(ws + 31457280);      //  0.10 MB
  float* pstats = (float*)(ws + 31555584);      //  0.79 MB
  float* part   = (float*)(ws + 32342016);      // 12.58 MB (2 x M*N partials)
  float* U      = (float*)(ws + 44924928);      // 50.33 MB union {scores|h1|xn}
  float* scores = U;
  float* h1     = U;
  float* xn     = U;
  const int PN = SEQ * D_MODEL;

  embed_kernel<<<6144, 256, 0, stream>>>(idx, tok_emb, pos_emb, x);

  for (int l = 0; l < NL; l++) {
    const float* wqkv = Wqkv + (size_t)l * D_MODEL * D3;
    const float* bq   = bqkv + (size_t)l * D3;
    const float* wo   = Wo   + (size_t)l * D_MODEL * D_MODEL;
    const float* bo_  = bo   + (size_t)l * D_MODEL;
    const float* w1   = W1   + (size_t)l * D_MODEL * D4;
    const float* b1_  = b1   + (size_t)l * D4;
    const float* w2   = W2   + (size_t)l * D4 * D_MODEL;
    const float* b2_  = b2   + (size_t)l * D_MODEL;

    mgemm_kernel<128, false, false, 1><<<288, 256, 0, stream>>>(
        x, wqkv, bq, nullptr, qkv, SEQ, D3, D_MODEL, 36, 8);
    scores_kernel<<<768, 256, 0, stream>>>(qkv, scores);
    colstatA_kernel<<<384, 256, 0, stream>>>(scores, pstats);
    colstatB_kernel<<<48, 256, 0, stream>>>(pstats, stats);
    av_kernel<<<384, 256, 0, stream>>>(qkv, scores, stats, part);
    combine_kernel<false, false, false><<<1536, 256, 0, stream>>>(
        part, part + PN, nullptr, nullptr, o, D_MODEL);
    mgemm_kernel<64, false, false, 2><<<384, 256, 0, stream>>>(
        o, wo, nullptr, nullptr, part, SEQ, D_MODEL, D_MODEL, 12, 16);
    combine_kernel<true, true, false><<<1536, 256, 0, stream>>>(
        part, part + PN, bo_, x, x, D_MODEL);
    mgemm_kernel<128, true, false, 1><<<384, 256, 0, stream>>>(
        x, w1, b1_, nullptr, h1, SEQ, D4, D_MODEL, 48, 8);
    mgemm_kernel<64, false, false, 2><<<384, 256, 0, stream>>>(
        h1, w2, nullptr, nullptr, part, SEQ, D_MODEL, D4, 12, 16);
    combine_kernel<true, true, false><<<1536, 256, 0, stream>>>(
        part, part + PN, b2_, x, x, D_MODEL);
  }

  ln_kernel<<<SEQ, 256, 0, stream>>>(x, ln_g, ln_b, xn);
  mgemm_kernel<64, false, false, 2><<<384, 256, 0, stream>>>(
      xn, Wout, nullptr, nullptr, part, SEQ, D_MODEL, D_MODEL, 12, 16);
  combine_kernel<true, false, false><<<1536, 256, 0, stream>>>(
      part, part + PN, bout, nullptr, out, D_MODEL);
}